// Round 3
// baseline (129.914 us; speedup 1.0000x reference)
//
#include <hip/hip_runtime.h>
#include <math.h>

#ifndef M_PI
#define M_PI 3.14159265358979323846
#endif

#define DMODEL 256
#define NSTATE 64
#define LSEQ   8192
#define INVL   (1.0f/8192.0f)

// Workspace layout (bytes). Total ~17.6 MB.
#define OFF_TW  0                                  // float2[6144]: e^{+2pi i j/L}
#define OFF_DN  (6144*8)                           // float4[3*DMODEL*NSTATE]
#define OFF_CDT (OFF_DN + DMODEL*NSTATE*48)        // float[DMODEL]: 2/dt
#define OFF_KT  (OFF_CDT + 1024)                   // float4[DMODEL*4096]: radix-2'd, digit-reversed K_hat/L

__device__ __forceinline__ float sin_rev(float r) {
#if __has_builtin(__builtin_amdgcn_sinf)
  return __builtin_amdgcn_sinf(r);        // sin(S0 * 2pi)
#else
  return __sinf(r * 6.283185307179586f);
#endif
}
__device__ __forceinline__ float cos_rev(float r) {
#if __has_builtin(__builtin_amdgcn_cosf)
  return __builtin_amdgcn_cosf(r);
#else
  return __cosf(r * 6.283185307179586f);
#endif
}

__device__ __forceinline__ float2 cmul(float2 a, float2 b) {
  return make_float2(a.x*b.x - a.y*b.y, a.x*b.y + a.y*b.x);
}

// K_hat/L from the 4 complex sums. PRB*BRP = S1^2 + S2^2 (complex squares).
// Prefactor 2/(1+z) = 1 + i*T; fold 1/L here.
__device__ __forceinline__ float2 woodbury(float2 S1, float2 S2, float2 S3,
                                           float2 S4, float T) {
  float nr = (S1.x*S1.x - S1.y*S1.y) + (S2.x*S2.x - S2.y*S2.y);
  float ni = 2.0f*(S1.x*S1.y + S2.x*S2.y);
  float dr = 1.0f + S3.x, di = S3.y;
  float inv = __builtin_amdgcn_rcpf(fmaf(dr, dr, di*di));
  float qr = (nr*dr + ni*di) * inv;
  float qi = (ni*dr - nr*di) * inv;
  float vr = S4.x - qr, vi = S4.y - qi;
  return make_float2((vr - T*vi)*INVL, (vi + T*vr)*INVL);
}

// ---------------------------------------------------------------- precompute
__global__ __launch_bounds__(256) void precompute_kernel(
    const float* __restrict__ Lre, const float* __restrict__ Lim,
    const float* __restrict__ Pre, const float* __restrict__ Pim,
    const float* __restrict__ Bre, const float* __restrict__ Bim,
    const float* __restrict__ log_dt, char* __restrict__ ws)
{
  const int t = blockIdx.x * blockDim.x + threadIdx.x;  // 0..16383
  float2* tw  = (float2*)(ws + OFF_TW);
  float4* dn  = (float4*)(ws + OFF_DN);
  float*  cdt = (float*)(ws + OFF_CDT);

  if (t < 6144) {
    double th = (2.0 * M_PI / (double)LSEQ) * (double)t;
    double s, c; sincos(th, &s, &c);
    tw[t] = make_float2((float)c, (float)s);
  }
  {
    float lre = Lre[t], lim = Lim[t];
    float pre = Pre[t], pim = Pim[t];
    float bre = Bre[t], bim = Bim[t];
    float sp = fmaxf(lre, 0.0f) + log1pf(expf(-fabsf(lre)));  // softplus
    float w1r = pre*bre + pim*bim;   // Re conj(P)*B
    float w1i = pre*bim - pim*bre;   // Im conj(P)*B
    float w2  = pre*pre + pim*pim;   // |P|^2
    float w3  = bre*bre + bim*bim;   // |B|^2
    dn[3*t]   = make_float4(lim, sp*sp, w1r*sp, w1i*sp);
    dn[3*t+1] = make_float4(w2*sp, w3*sp, w1r, w1i);
    dn[3*t+2] = make_float4(w2, w3, 0.0f, 0.0f);
  }
  if (t < DMODEL) cdt[t] = 2.0f * expf(-log_dt[t]);
}

// ---------------------------------------------------------------- cauchy
// No LDS -> 8 waves/SIMD. Thread = pair (kA, kA+4096) with kA = digit-reversed
// position; writes post-radix-2 {sum, diff} linearly (the FFT's natural input).
__global__ __launch_bounds__(256, 8) void cauchy_kernel(
    const float4* __restrict__ dn_all, const float* __restrict__ cdt,
    float4* __restrict__ kt)
{
  const int d = blockIdx.y;
  const int b = blockIdx.x * 256 + threadIdx.x;   // 0..4095 pair id
  const float4* dn = dn_all + (size_t)d * (3*NSTATE);
  const float c = cdt[d];                         // 2/dt, wave-uniform

  const unsigned p = (unsigned)(2*b);
  const unsigned r = __brev(p) >> 19;             // 13-bit reversal (r < 4096)
  const int kA = (int)(((r & 0x0555u) << 1) | ((r & 0x0AAAu) >> 1));  // pair-swap
  // T = tan(pi k/L); (1-z)/(1+z) = i*T, 2/(1+z) = 1 + i*T (exact identities)
  const float rev = (float)kA * (1.0f/16384.0f);  // < 0.25 revolutions
  const float sA = sin_rev(rev), cA = cos_rev(rev);
  float TA = sA * __builtin_amdgcn_rcpf(cA);
  float TB = -cA * __builtin_amdgcn_rcpf(sA);     // tan(x + pi/2) = -cot(x)
  TA = fminf(fmaxf(TA, -1e7f), 1e7f);
  TB = fminf(fmaxf(TB, -1e7f), 1e7f);
  const float gA = c * TA, gB = c * TB;           // g purely imaginary

  float2 S1a = {0,0}, S2a = {0,0}, S3a = {0,0}, S4a = {0,0};
  float2 S1b = {0,0}, S2b = {0,0}, S3b = {0,0}, S4b = {0,0};
#pragma unroll 4
  for (int n = 0; n < NSTATE; ++n) {
    const float4 q0 = dn[3*n];      // lam_im, sp^2, w1r*sp, w1i*sp  (s_load)
    const float4 q1 = dn[3*n+1];    // w2*sp, w3*sp, w1r, w1i
    const float4 q2 = dn[3*n+2];    // w2, w3, -, -
    {
      const float dim = gA - q0.x;
      const float inv = __builtin_amdgcn_rcpf(fmaf(dim, dim, q0.y));
      const float dI  = dim * inv;
      S1a.x = fmaf(q0.z, inv, S1a.x);  S1a.y = fmaf(q1.z, -dI, S1a.y);
      S2a.x = fmaf(q0.w, inv, S2a.x);  S2a.y = fmaf(q1.w, -dI, S2a.y);
      S3a.x = fmaf(q1.x, inv, S3a.x);  S3a.y = fmaf(q2.x, -dI, S3a.y);
      S4a.x = fmaf(q1.y, inv, S4a.x);  S4a.y = fmaf(q2.y, -dI, S4a.y);
    }
    {
      const float dim = gB - q0.x;
      const float inv = __builtin_amdgcn_rcpf(fmaf(dim, dim, q0.y));
      const float dI  = dim * inv;
      S1b.x = fmaf(q0.z, inv, S1b.x);  S1b.y = fmaf(q1.z, -dI, S1b.y);
      S2b.x = fmaf(q0.w, inv, S2b.x);  S2b.y = fmaf(q1.w, -dI, S2b.y);
      S3b.x = fmaf(q1.x, inv, S3b.x);  S3b.y = fmaf(q2.x, -dI, S3b.y);
      S4b.x = fmaf(q1.y, inv, S4b.x);  S4b.y = fmaf(q2.y, -dI, S4b.y);
    }
  }
  const float2 KA = woodbury(S1a, S2a, S3a, S4a, TA);
  const float2 KB = woodbury(S1b, S2b, S3b, S4b, TB);
  kt[(size_t)d * 4096 + b] = make_float4(KA.x + KB.x, KA.y + KB.y,
                                         KA.x - KB.x, KA.y - KB.y);
}

// ---------------------------------------------------------------- ifft
// Input is already radix-2'd and digit-reversed -> linear float4 load,
// 6 radix-4 DIT stages in LDS, natural-order real output.
__global__ __launch_bounds__(1024) void ifft_kernel(
    const float4* __restrict__ kt, const float2* __restrict__ tw,
    const float* __restrict__ Din, float* __restrict__ out)
{
  __shared__ __align__(16) float2 xy[LSEQ];   // 64 KB
  const int d = blockIdx.x;
  const int t = threadIdx.x;                  // 0..1023
  const float4* row = kt + (size_t)d * 4096;

  for (int i = t; i < 4096; i += 1024) ((float4*)xy)[i] = row[i];
  __syncthreads();

#pragma unroll
  for (int s = 0; s < 6; ++s) {
    const int h = 2 << (2*s);
    const int twsh = 10 - 2*s;                // tw stride = L/(4h)
#pragma unroll
    for (int j = 0; j < 2; ++j) {
      const int bb = t + (j << 10);           // butterfly id 0..2047
      const int pos = bb & (h - 1);
      const int i0 = ((bb >> (1 + 2*s)) << (3 + 2*s)) + pos;
      const int ti = pos << twsh;
      const float2 w1 = tw[ti];
      const float2 w2 = tw[2*ti];
      const float2 w3 = tw[3*ti];
      const float2 x0 = xy[i0];
      const float2 x1 = xy[i0 + h];
      const float2 x2 = xy[i0 + 2*h];
      const float2 x3 = xy[i0 + 3*h];
      const float2 t1 = cmul(w1, x1);
      const float2 t2 = cmul(w2, x2);
      const float2 t3 = cmul(w3, x3);
      const float2 u0 = make_float2(x0.x + t2.x, x0.y + t2.y);
      const float2 u1 = make_float2(x0.x - t2.x, x0.y - t2.y);
      const float2 u2 = make_float2(t1.x + t3.x, t1.y + t3.y);
      const float2 vv = make_float2(t1.x - t3.x, t1.y - t3.y);
      xy[i0]         = make_float2(u0.x + u2.x, u0.y + u2.y);   // Y0
      xy[i0 + h]     = make_float2(u1.x - vv.y, u1.y + vv.x);   // Y1 = u1 + i*vv
      xy[i0 + 2*h]   = make_float2(u0.x - u2.x, u0.y - u2.y);   // Y2
      xy[i0 + 3*h]   = make_float2(u1.x + vv.y, u1.y - vv.x);   // Y3 = u1 - i*vv
    }
    __syncthreads();
  }

  float* orow = out + (size_t)d * LSEQ;
  for (int i = t; i < LSEQ; i += 1024) orow[i] = xy[i].x;

  // second tuple output: D passthrough (zeros buffer)
  if (d == 0 && t < DMODEL) out[(size_t)DMODEL * LSEQ + t] = Din[t];
}

// ---------------------------------------------------------------- launch
extern "C" void kernel_launch(void* const* d_in, const int* in_sizes, int n_in,
                              void* d_out, int out_size, void* d_ws, size_t ws_size,
                              hipStream_t stream)
{
  const float* Lre    = (const float*)d_in[0];
  const float* Lim    = (const float*)d_in[1];
  const float* Pre    = (const float*)d_in[2];
  const float* Pim    = (const float*)d_in[3];
  const float* Bre    = (const float*)d_in[4];
  const float* Bim    = (const float*)d_in[5];
  const float* log_dt = (const float*)d_in[6];
  const float* Din    = (const float*)d_in[7];
  float* out = (float*)d_out;
  char* ws = (char*)d_ws;

  hipLaunchKernelGGL(precompute_kernel, dim3(64), dim3(256), 0, stream,
                     Lre, Lim, Pre, Pim, Bre, Bim, log_dt, ws);
  hipLaunchKernelGGL(cauchy_kernel, dim3(16, DMODEL), dim3(256), 0, stream,
                     (const float4*)(ws + OFF_DN), (const float*)(ws + OFF_CDT),
                     (float4*)(ws + OFF_KT));
  hipLaunchKernelGGL(ifft_kernel, dim3(DMODEL), dim3(1024), 0, stream,
                     (const float4*)(ws + OFF_KT), (const float2*)(ws + OFF_TW),
                     Din, out);
}